// Round 4
// baseline (316.784 us; speedup 1.0000x reference)
//
#include <hip/hip_runtime.h>
#include <hip/hip_bf16.h>

// N=4, C=256, H=W=64 -> HW=4096, E=128, 3E=384.
// qkv flat [n][o][hw] IS [n][p][384]: q=p*384+0..127, k=+128, v=+256.
// attn flat [n][i*128+d] reinterpreted as [n][e][hw] by k_oproj (raw reshape).
// Softmax over i (columns): lse_j precomputed; exp(-lse_j) folded into V (k_vtrans).

typedef short bfrag __attribute__((ext_vector_type(8)));   // 8 bf16 (4 VGPRs)
typedef float ffrag __attribute__((ext_vector_type(4)));   // 4 fp32 acc
typedef unsigned short us4 __attribute__((ext_vector_type(4)));
#define MFMA(a,b,c) __builtin_amdgcn_mfma_f32_16x16x32_bf16((a),(b),(c),0,0,0)

__device__ __forceinline__ unsigned short f2bf(float f){
  union { float f; unsigned u; } v; v.f = f;
  unsigned r = v.u + 0x7fffu + ((v.u >> 16) & 1u);   // RNE
  return (unsigned short)(r >> 16);
}
__device__ __forceinline__ float bf2f(unsigned short h){
  union { unsigned u; float f; } v; v.u = ((unsigned)h) << 16; return v.f;
}
__device__ __forceinline__ unsigned bfpack(float a, float b){
  return (unsigned)f2bf(a) | ((unsigned)f2bf(b) << 16);
}

// ---------------- K0: cast weights to bf16 ----------------
__global__ __launch_bounds__(256) void k_wcast(const float* __restrict__ Wq, const float* __restrict__ Wo,
                                               unsigned short* __restrict__ Wqb, unsigned short* __restrict__ Wob){
  int i = blockIdx.x*256 + threadIdx.x;
  if (i < 384*256) Wqb[i] = f2bf(Wq[i]);
  if (i < 256*128) Wob[i] = f2bf(Wo[i]);
}

// ---------------- K1: QKV projection (D[m=hw][n=o] -> ushort4 stores) ----------------
__global__ __launch_bounds__(256) void k_qkv(const float* __restrict__ x, const unsigned short* __restrict__ Wqb,
                                             const float* __restrict__ bq, unsigned short* __restrict__ qkv){
  constexpr int LD = 136;
  __shared__ __align__(16) unsigned short As[64*LD];   // W tile [o][c-half]
  __shared__ __align__(16) unsigned short Bs[64*LD];   // X^T tile [hw][c-half]
  const int o0 = blockIdx.x*64, h0 = blockIdx.y*64, n = blockIdx.z;
  const int t = threadIdx.x, w = t>>6, lane = t&63, lr = lane&15, q4 = lane>>4;
  ffrag acc[4] = {};
  for (int kh = 0; kh < 2; ++kh) {
    __syncthreads();
    #pragma unroll
    for (int r=0;r<4;++r){
      int pi = t + 256*r; int o = pi>>4, seg = pi&15;
      *(uint4*)&As[o*LD + seg*8] = *(const uint4*)(Wqb + (o0+o)*256 + kh*128 + seg*8);
    }
    #pragma unroll
    for (int r=0;r<32;++r){
      int idx = t + 256*r; int cl = idx>>6, hl = idx&63;
      float v = x[(size_t)(n*256 + kh*128 + cl)*4096 + h0 + hl];
      Bs[hl*LD + cl] = f2bf(v);
    }
    __syncthreads();
    #pragma unroll
    for (int kk=0;kk<4;++kk){
      bfrag a = *(const bfrag*)&Bs[(w*16+lr)*LD + kk*32 + q4*8];   // A = x^T rows (hw)
      #pragma unroll
      for (int ot=0;ot<4;++ot){
        bfrag b = *(const bfrag*)&As[(ot*16+lr)*LD + kk*32 + q4*8]; // B = W rows (o)
        acc[ot] = MFMA(a,b,acc[ot]);                                // D[m=hw][n=o]
      }
    }
  }
  size_t base = (size_t)n*384*4096;
  #pragma unroll
  for (int ot=0;ot<4;++ot){
    int o  = o0 + ot*16 + lr;
    float bias = bq[o];
    int hw = h0 + w*16 + q4*4;
    us4 pk;
    pk.x = f2bf(acc[ot][0] + bias); pk.y = f2bf(acc[ot][1] + bias);
    pk.z = f2bf(acc[ot][2] + bias); pk.w = f2bf(acc[ot][3] + bias);
    *(us4*)(qkv + base + (size_t)o*4096 + hw) = pk;
  }
}

// ---------------- K2: column stats — zero LDS, zero barriers ----------------
// Each wave owns 16 j-columns; K frags loop-invariant in registers, Q frags from global (L2).
__global__ __launch_bounds__(256) void k_stats(const unsigned short* __restrict__ qkv,
                                               float* __restrict__ mp, float* __restrict__ zp){
  const int j0 = blockIdx.x*64, ic = blockIdx.y, n = blockIdx.z;
  const int t = threadIdx.x, w = t>>6, lane = t&63, lr = lane&15, q4 = lane>>4;
  size_t base = (size_t)n*384*4096;
  bfrag kf[4];
  {
    const unsigned short* krow = qkv + base + (size_t)(j0 + w*16 + lr)*384 + 128;
    #pragma unroll
    for (int kk=0;kk<4;++kk) kf[kk] = *(const bfrag*)(krow + kk*32 + q4*8);
  }
  float m0=-3.0e38f,m1=-3.0e38f,m2=-3.0e38f,m3=-3.0e38f;
  float Z0=0.f,Z1=0.f,Z2=0.f,Z3=0.f;
  const float inv64 = 0.015625f;
  #pragma unroll 4
  for (int it=0; it<64; ++it){
    const unsigned short* arow = qkv + base + (size_t)((ic<<10) + it*16 + lr)*384;
    ffrag s = {};
    #pragma unroll
    for (int kk=0;kk<4;++kk){
      bfrag a = *(const bfrag*)(arow + kk*32 + q4*8);   // A[m=i][k=d] direct from global
      s = MFMA(a, kf[kk], s);                           // D[m=i][n=j]
    }
    float s0=s[0]*inv64, s1=s[1]*inv64, s2=s[2]*inv64, s3=s[3]*inv64;
    float tm = fmaxf(fmaxf(s0,s1), fmaxf(s2,s3));
    tm = fmaxf(tm, __shfl_xor(tm, 16));
    tm = fmaxf(tm, __shfl_xor(tm, 32));
    float se = __expf(s0-tm)+__expf(s1-tm)+__expf(s2-tm)+__expf(s3-tm);
    se += __shfl_xor(se, 16);
    se += __shfl_xor(se, 32);
    // 4 independent online chains (it&3) to break the serial dependency
    int c = it & 3;
    if (c==0){ float nm = fmaxf(m0,tm); Z0 = Z0*__expf(m0-nm) + se*__expf(tm-nm); m0 = nm; }
    else if (c==1){ float nm = fmaxf(m1,tm); Z1 = Z1*__expf(m1-nm) + se*__expf(tm-nm); m1 = nm; }
    else if (c==2){ float nm = fmaxf(m2,tm); Z2 = Z2*__expf(m2-nm) + se*__expf(tm-nm); m2 = nm; }
    else        { float nm = fmaxf(m3,tm); Z3 = Z3*__expf(m3-nm) + se*__expf(tm-nm); m3 = nm; }
  }
  float M = fmaxf(fmaxf(m0,m1), fmaxf(m2,m3));
  float Zt = Z0*__expf(m0-M) + Z1*__expf(m1-M) + Z2*__expf(m2-M) + Z3*__expf(m3-M);
  if (lane < 16){
    int idx = (((n<<2)+ic)<<12) + j0 + w*16 + lane;
    mp[idx] = M; zp[idx] = Zt;
  }
}

// ---------------- K3: merge partial stats -> lse[n][j] = m + log Z ----------------
__global__ __launch_bounds__(256) void k_merge(const float* __restrict__ mp, const float* __restrict__ zp,
                                               float* __restrict__ lse){
  int idx = blockIdx.x*256 + threadIdx.x;
  int n = idx>>12, j = idx&4095;
  float m = -3.0e38f, Z = 0.f;
  #pragma unroll
  for (int c=0;c<4;++c){
    int k = (((n<<2)+c)<<12) + j;
    float mc = mp[k], zc = zp[k];
    float nm = fmaxf(m, mc);
    Z = Z*__expf(m-nm) + zc*__expf(mc-nm);
    m = nm;
  }
  lse[idx] = m + __logf(Z);
}

// ---------------- K4: V transpose + fold exp(-lse): vt[n][d][p] = v[n][p][d]*exp(-lse[p]) ----------------
__global__ __launch_bounds__(256) void k_vtrans(const unsigned short* __restrict__ qkv,
                                                const float* __restrict__ lse,
                                                unsigned short* __restrict__ vt){
  constexpr int LD = 136;
  __shared__ __align__(16) unsigned short T[64*LD];
  __shared__ float Sc[64];
  const int p0 = blockIdx.x*64, n = blockIdx.y;
  const int t = threadIdx.x;
  size_t base = (size_t)n*384*4096;
  #pragma unroll
  for (int r=0;r<4;++r){
    int pi = t + 256*r; int pl = pi>>4, seg = pi&15;
    *(uint4*)&T[pl*LD + seg*8] = *(const uint4*)(qkv + base + (size_t)(p0+pl)*384 + 256 + seg*8);
  }
  if (t < 64) Sc[t] = __expf(-lse[(n<<12) + p0 + t]);
  __syncthreads();
  unsigned* vt32 = (unsigned*)(vt + (size_t)n*128*4096);
  #pragma unroll
  for (int r=0;r<16;++r){
    int pi = t + 256*r;            // 4096 = 128 d x 32 p-pairs
    int d = pi>>5, k = pi&31;
    float lo = bf2f(T[(2*k)*LD + d])   * Sc[2*k];
    float hi = bf2f(T[(2*k+1)*LD + d]) * Sc[2*k+1];
    vt32[(size_t)d*2048 + (p0>>1) + k] = bfpack(lo, hi);
  }
}

// ---------------- K5: PV pass, 512 thr, i-tile 128, jh=4, bf16 partials ----------------
// QK: D[m=j][n=i] = MFMA(K,Q); P = exp(s/64) (lse folded into V'); PV: D[m=d][n=i] = MFMA(V',P)
__global__ __launch_bounds__(512) void k_attn(const unsigned short* __restrict__ qkv,
                                              const unsigned short* __restrict__ vtg_all,
                                              unsigned short* __restrict__ part){
  constexpr int LDK = 136, LDV = 72, LDP = 72;
  __shared__ __align__(16) unsigned short Ks[64*LDK];    // 17408 B
  __shared__ __align__(16) unsigned short Vt[128*LDV];   // 18432 B
  __shared__ __align__(16) unsigned short Pw[8][16*LDP]; // 18432 B
  const int i0 = blockIdx.x*128, jh = blockIdx.y, n = blockIdx.z;
  const int t = threadIdx.x, w = t>>6, lane = t&63, lr = lane&15, q4 = lane>>4;
  size_t base = (size_t)n*384*4096;
  const unsigned short* vtg = vtg_all + (size_t)n*128*4096;
  bfrag qf[4];   // Q row per (w,lr); serves as B[k=d][n=i]
  {
    const unsigned short* qrow = qkv + base + (size_t)(i0 + w*16 + lr)*384;
    #pragma unroll
    for (int kk=0;kk<4;++kk) qf[kk] = *(const bfrag*)(qrow + kk*32 + q4*8);
  }
  ffrag acc[8] = {};
  const float inv64 = 0.015625f;
  for (int j0 = jh*1024; j0 < jh*1024+1024; j0 += 64){
    __syncthreads();
    #pragma unroll
    for (int r=0;r<2;++r){                    // K rows j0..j0+63 (1024 uint4 / 512 thr)
      int pi = t + 512*r; int jl = pi>>4, seg = pi&15;
      *(uint4*)&Ks[jl*LDK + seg*8] = *(const uint4*)(qkv + base + (size_t)(j0+jl)*384 + 128 + seg*8);
    }
    #pragma unroll
    for (int r=0;r<2;++r){                    // Vt[128 d][64 j]
      int pi = t + 512*r; int d = pi>>3, c = pi&7;
      *(uint4*)&Vt[d*LDV + c*8] = *(const uint4*)(vtg + (size_t)d*4096 + j0 + c*8);
    }
    __syncthreads();
    #pragma unroll
    for (int jt=0;jt<4;++jt){
      ffrag s = {};
      #pragma unroll
      for (int kk=0;kk<4;++kk){
        bfrag kf = *(const bfrag*)&Ks[(jt*16+lr)*LDK + kk*32 + q4*8];  // A[m=j][k=d]
        s = MFMA(kf, qf[kk], s);               // D[m=j][n=i] = S^T tile
      }
      float p0 = __expf(s[0]*inv64);
      float p1 = __expf(s[1]*inv64);
      float p2 = __expf(s[2]*inv64);
      float p3 = __expf(s[3]*inv64);
      uint2 pk; pk.x = bfpack(p0,p1); pk.y = bfpack(p2,p3);
      *(uint2*)&Pw[w][lr*LDP + jt*16 + q4*4] = pk;   // P[i=lr][j] row, wave-private
    }
    asm volatile("" ::: "memory");             // no compiler reorder of Pw read above writes
    #pragma unroll
    for (int jk=0;jk<2;++jk){
      bfrag pf = *(const bfrag*)&Pw[w][lr*LDP + jk*32 + q4*8];         // B[k=j][n=i]
      #pragma unroll
      for (int dt=0;dt<8;++dt){
        bfrag af = *(const bfrag*)&Vt[(dt*16+lr)*LDV + jk*32 + q4*8];  // A[m=d][k=j]
        acc[dt] = MFMA(af, pf, acc[dt]);       // D[m=d][n=i]
      }
    }
  }
  unsigned short* po = part + (size_t)(jh*4+n)*4096*128;
  const int i = i0 + w*16 + lr;
  #pragma unroll
  for (int dt=0;dt<8;++dt){
    us4 pk;
    pk.x = f2bf(acc[dt][0]); pk.y = f2bf(acc[dt][1]);
    pk.z = f2bf(acc[dt][2]); pk.w = f2bf(acc[dt][3]);
    *(us4*)(po + (size_t)i*128 + dt*16 + q4*4) = pk;
  }
}

// ---------------- K6: output projection, sums 4 bf16 partial slices, c-tile 128 ----------------
__global__ __launch_bounds__(256) void k_oproj(const unsigned short* __restrict__ part,
                                               const unsigned short* __restrict__ Wob,
                                               const float* __restrict__ bo, float* __restrict__ y){
  constexpr int LD = 136;
  __shared__ __align__(16) unsigned short As[128*LD];  // Wo tile [c][e]
  __shared__ __align__(16) unsigned short Rt[64*LD];   // attn^T [hw][e]
  const int c0 = blockIdx.x*128, h0 = blockIdx.y*64, n = blockIdx.z;
  const int t = threadIdx.x, w = t>>6, lane = t&63, lr = lane&15, q4 = lane>>4;
  #pragma unroll
  for (int r=0;r<8;++r){
    int pi = t + 256*r; int cl = pi>>4, seg = pi&15;
    *(uint4*)&As[cl*LD + seg*8] = *(const uint4*)(Wob + (c0+cl)*128 + seg*8);
  }
  #pragma unroll
  for (int r=0;r<8;++r){                     // 2048 = 128 e x 16 h-quads
    int pi = t + 256*r; int e = pi>>4, h4 = pi&15;
    size_t f = (size_t)e*4096 + h0 + h4*4;
    float a0=0.f,a1=0.f,a2=0.f,a3=0.f;
    #pragma unroll
    for (int s=0;s<4;++s){
      uint2 u = *(const uint2*)(part + (size_t)(s*4+n)*524288 + f);
      a0 += bf2f((unsigned short)(u.x & 0xffffu));
      a1 += bf2f((unsigned short)(u.x >> 16));
      a2 += bf2f((unsigned short)(u.y & 0xffffu));
      a3 += bf2f((unsigned short)(u.y >> 16));
    }
    Rt[(h4*4+0)*LD + e] = f2bf(a0);
    Rt[(h4*4+1)*LD + e] = f2bf(a1);
    Rt[(h4*4+2)*LD + e] = f2bf(a2);
    Rt[(h4*4+3)*LD + e] = f2bf(a3);
  }
  __syncthreads();
  ffrag acc[8] = {};
  #pragma unroll
  for (int kk=0;kk<4;++kk){
    bfrag a = *(const bfrag*)&Rt[(w*16+lr)*LD + kk*32 + q4*8];   // A = attn^T rows (hw)
    #pragma unroll
    for (int cs=0;cs<8;++cs){
      bfrag b = *(const bfrag*)&As[(cs*16+lr)*LD + kk*32 + q4*8]; // B = Wo rows (c)
      acc[cs] = MFMA(a,b,acc[cs]);                                // D[m=hw][n=c]
    }
  }
  #pragma unroll
  for (int cs=0;cs<8;++cs){
    int c = c0 + cs*16 + lr;
    float bias = bo[c];
    float4 v4 = { acc[cs][0]+bias, acc[cs][1]+bias, acc[cs][2]+bias, acc[cs][3]+bias };
    *(float4*)(y + ((size_t)n*256 + c)*4096 + h0 + w*16 + q4*4) = v4;
  }
}

extern "C" void kernel_launch(void* const* d_in, const int* in_sizes, int n_in,
                              void* d_out, int out_size, void* d_ws, size_t ws_size,
                              hipStream_t stream){
  const float* x  = (const float*)d_in[0];
  const float* Wq = (const float*)d_in[1];
  const float* bq = (const float*)d_in[2];
  const float* Wo = (const float*)d_in[3];
  const float* bo = (const float*)d_in[4];
  float* y = (float*)d_out;
  char* ws = (char*)d_ws;
  unsigned short* qkv  = (unsigned short*)(ws + 0);          // 12,582,912
  unsigned short* vtg  = (unsigned short*)(ws + 12582912);   //  4,194,304
  unsigned short* Wqb  = (unsigned short*)(ws + 16777216);   //    196,608
  unsigned short* Wob  = (unsigned short*)(ws + 16973824);   //     65,536
  float* mp   = (float*)(ws + 17039360);                     //    262,144
  float* zp   = (float*)(ws + 17301504);                     //    262,144
  float* lse  = (float*)(ws + 17563648);                     //     65,536
  unsigned short* part = (unsigned short*)(ws + 17629184);   // 16,777,216 (4 bf16 slices) end ~34.4MB

  k_wcast <<<dim3(384),     256, 0, stream>>>(Wq, Wo, Wqb, Wob);
  k_qkv   <<<dim3(6,64,4),  256, 0, stream>>>(x, Wqb, bq, qkv);
  k_stats <<<dim3(64,4,4),  256, 0, stream>>>(qkv, mp, zp);
  k_merge <<<dim3(64),      256, 0, stream>>>(mp, zp, lse);
  k_vtrans<<<dim3(64,4),    256, 0, stream>>>(qkv, lse, vtg);
  k_attn  <<<dim3(32,4,4),  512, 0, stream>>>(qkv, vtg, part);
  k_oproj <<<dim3(2,64,4),  256, 0, stream>>>(part, Wob, bo, y);
}

// Round 5
// 289.542 us; speedup vs baseline: 1.0941x; 1.0941x over previous
//
#include <hip/hip_runtime.h>
#include <hip/hip_bf16.h>

// N=4, C=256, H=W=64 -> HW=4096, E=128, 3E=384.
// qkv flat [n][o][hw] IS [n][p][384]: q=p*384+0..127, k=+128, v=+256.
// attn flat [n][i*128+d] reinterpreted as [n][e][hw] by k_oproj (raw reshape).
// Column softmax (over i): scores bounded (|s|<~1.2) -> direct sum-exp, no max tracking.
// exp(-lse_j) folded into V' (k_vtrans), so k_attn's P = exp(s/64) needs no lse.

typedef short bfrag __attribute__((ext_vector_type(8)));   // 8 bf16 (4 VGPRs)
typedef float ffrag __attribute__((ext_vector_type(4)));   // 4 fp32 acc
typedef unsigned short us4 __attribute__((ext_vector_type(4)));
#define MFMA(a,b,c) __builtin_amdgcn_mfma_f32_16x16x32_bf16((a),(b),(c),0,0,0)

__device__ __forceinline__ unsigned short f2bf(float f){
  union { float f; unsigned u; } v; v.f = f;
  unsigned r = v.u + 0x7fffu + ((v.u >> 16) & 1u);   // RNE
  return (unsigned short)(r >> 16);
}
__device__ __forceinline__ float bf2f(unsigned short h){
  union { unsigned u; float f; } v; v.u = ((unsigned)h) << 16; return v.f;
}
__device__ __forceinline__ unsigned bfpack(float a, float b){
  return (unsigned)f2bf(a) | ((unsigned)f2bf(b) << 16);
}

// ---------------- K0: cast weights to bf16 ----------------
__global__ __launch_bounds__(256) void k_wcast(const float* __restrict__ Wq, const float* __restrict__ Wo,
                                               unsigned short* __restrict__ Wqb, unsigned short* __restrict__ Wob){
  int i = blockIdx.x*256 + threadIdx.x;
  if (i < 384*256) Wqb[i] = f2bf(Wq[i]);
  if (i < 256*128) Wob[i] = f2bf(Wo[i]);
}

// ---------------- K1: QKV projection (D[m=hw][n=o] -> ushort4 stores) ----------------
__global__ __launch_bounds__(256) void k_qkv(const float* __restrict__ x, const unsigned short* __restrict__ Wqb,
                                             const float* __restrict__ bq, unsigned short* __restrict__ qkv){
  constexpr int LD = 136;
  __shared__ __align__(16) unsigned short As[64*LD];   // W tile [o][c-half]
  __shared__ __align__(16) unsigned short Bs[64*LD];   // X^T tile [hw][c-half]
  const int o0 = blockIdx.x*64, h0 = blockIdx.y*64, n = blockIdx.z;
  const int t = threadIdx.x, w = t>>6, lane = t&63, lr = lane&15, q4 = lane>>4;
  ffrag acc[4] = {};
  for (int kh = 0; kh < 2; ++kh) {
    __syncthreads();
    #pragma unroll
    for (int r=0;r<4;++r){
      int pi = t + 256*r; int o = pi>>4, seg = pi&15;
      *(uint4*)&As[o*LD + seg*8] = *(const uint4*)(Wqb + (o0+o)*256 + kh*128 + seg*8);
    }
    #pragma unroll
    for (int r=0;r<32;++r){
      int idx = t + 256*r; int cl = idx>>6, hl = idx&63;
      float v = x[(size_t)(n*256 + kh*128 + cl)*4096 + h0 + hl];
      Bs[hl*LD + cl] = f2bf(v);
    }
    __syncthreads();
    #pragma unroll
    for (int kk=0;kk<4;++kk){
      bfrag a = *(const bfrag*)&Bs[(w*16+lr)*LD + kk*32 + q4*8];   // A = x^T rows (hw)
      #pragma unroll
      for (int ot=0;ot<4;++ot){
        bfrag b = *(const bfrag*)&As[(ot*16+lr)*LD + kk*32 + q4*8]; // B = W rows (o)
        acc[ot] = MFMA(a,b,acc[ot]);                                // D[m=hw][n=o]
      }
    }
  }
  size_t base = (size_t)n*384*4096;
  #pragma unroll
  for (int ot=0;ot<4;++ot){
    int o  = o0 + ot*16 + lr;
    float bias = bq[o];
    int hw = h0 + w*16 + q4*4;
    us4 pk;
    pk.x = f2bf(acc[ot][0] + bias); pk.y = f2bf(acc[ot][1] + bias);
    pk.z = f2bf(acc[ot][2] + bias); pk.w = f2bf(acc[ot][3] + bias);
    *(us4*)(qkv + base + (size_t)o*4096 + hw) = pk;
  }
}

// ---------------- K2: column Z partials: Z_j = sum_i exp(q_i.k_j/64) ----------------
// No max (scores bounded). Wave owns 32 j (K frags in regs); Q staged in LDS, each
// Q B-frag read feeds 2 MFMAs. Per-lane Z accumulators, one shuffle-reduce at end.
__global__ __launch_bounds__(256) void k_stats(const unsigned short* __restrict__ qkv,
                                               float* __restrict__ zp){
  constexpr int LD = 136;
  __shared__ __align__(16) unsigned short Qs[64*LD];   // 17408 B
  const int j0 = blockIdx.x*128, ic = blockIdx.y, n = blockIdx.z;
  const int t = threadIdx.x, w = t>>6, lane = t&63, lr = lane&15, q4 = lane>>4;
  size_t base = (size_t)n*384*4096;
  bfrag kf[2][4];
  #pragma unroll
  for (int js=0; js<2; ++js){
    const unsigned short* krow = qkv + base + (size_t)(j0 + w*32 + js*16 + lr)*384 + 128;
    #pragma unroll
    for (int kk=0;kk<4;++kk) kf[js][kk] = *(const bfrag*)(krow + kk*32 + q4*8);
  }
  float Zc[8] = {};                       // [js*4 + r]
  const float inv64 = 0.015625f;
  for (int rnd=0; rnd<8; ++rnd){          // 8 x 64-i stage rounds (ic chunk = 512 i)
    int i0 = (ic<<9) + rnd*64;
    __syncthreads();
    #pragma unroll
    for (int r=0;r<4;++r){
      int pi = t + 256*r; int il = pi>>4, seg = pi&15;
      *(uint4*)&Qs[il*LD + seg*8] = *(const uint4*)(qkv + base + (size_t)(i0+il)*384 + seg*8);
    }
    __syncthreads();
    #pragma unroll
    for (int it=0; it<4; ++it){
      bfrag qb[4];
      #pragma unroll
      for (int kk=0;kk<4;++kk) qb[kk] = *(const bfrag*)&Qs[(it*16+lr)*LD + kk*32 + q4*8];
      #pragma unroll
      for (int js=0; js<2; ++js){
        ffrag s = {};
        #pragma unroll
        for (int kk=0;kk<4;++kk) s = MFMA(kf[js][kk], qb[kk], s);   // D[m=j][n=i]
        #pragma unroll
        for (int r=0;r<4;++r) Zc[js*4+r] += __expf(s[r]*inv64);
      }
    }
  }
  // reduce over the 16 i-lanes (lr) within each q4 group
  #pragma unroll
  for (int v=0; v<8; ++v){
    float z = Zc[v];
    z += __shfl_xor(z, 1); z += __shfl_xor(z, 2);
    z += __shfl_xor(z, 4); z += __shfl_xor(z, 8);
    Zc[v] = z;
  }
  if (lr == 0){
    int jb = j0 + w*32;
    float* zrow = zp + (size_t)((n<<3)+ic)*4096;
    #pragma unroll
    for (int js=0; js<2; ++js)
      #pragma unroll
      for (int r=0;r<4;++r)
        zrow[jb + js*16 + q4*4 + r] = Zc[js*4+r];
  }
}

// ---------------- K3: merge partial Z -> lse[n][j] = log(sum Z) ----------------
__global__ __launch_bounds__(256) void k_merge(const float* __restrict__ zp, float* __restrict__ lse){
  int idx = blockIdx.x*256 + threadIdx.x;   // n*4096 + j
  int n = idx>>12, j = idx&4095;
  float Z = 0.f;
  #pragma unroll
  for (int c=0;c<8;++c) Z += zp[(size_t)((n<<3)+c)*4096 + j];
  lse[idx] = __logf(Z);
}

// ---------------- K4: V transpose + fold exp(-lse): vt[n][d][p] = v[n][p][d]*exp(-lse[p]) ----------------
__global__ __launch_bounds__(256) void k_vtrans(const unsigned short* __restrict__ qkv,
                                                const float* __restrict__ lse,
                                                unsigned short* __restrict__ vt){
  constexpr int LD = 136;
  __shared__ __align__(16) unsigned short T[64*LD];
  __shared__ float Sc[64];
  const int p0 = blockIdx.x*64, n = blockIdx.y;
  const int t = threadIdx.x;
  size_t base = (size_t)n*384*4096;
  #pragma unroll
  for (int r=0;r<4;++r){
    int pi = t + 256*r; int pl = pi>>4, seg = pi&15;
    *(uint4*)&T[pl*LD + seg*8] = *(const uint4*)(qkv + base + (size_t)(p0+pl)*384 + 256 + seg*8);
  }
  if (t < 64) Sc[t] = __expf(-lse[(n<<12) + p0 + t]);
  __syncthreads();
  unsigned* vt32 = (unsigned*)(vt + (size_t)n*128*4096);
  #pragma unroll
  for (int r=0;r<16;++r){
    int pi = t + 256*r;            // 4096 = 128 d x 32 p-pairs
    int d = pi>>5, k = pi&31;
    float lo = bf2f(T[(2*k)*LD + d])   * Sc[2*k];
    float hi = bf2f(T[(2*k+1)*LD + d]) * Sc[2*k+1];
    vt32[(size_t)d*2048 + (p0>>1) + k] = bfpack(lo, hi);
  }
}

// ---------------- K5: PV pass (round-3 structure: 256 thr, i-tile 64, jh=2) ----------------
// QK: D[m=j][n=i] = MFMA(K,Q); P = exp(s/64); PV: D[m=d][n=i] = MFMA(V',P); bf16 partials.
__global__ __launch_bounds__(256) void k_attn(const unsigned short* __restrict__ qkv,
                                              const unsigned short* __restrict__ vtg_all,
                                              unsigned short* __restrict__ part){
  constexpr int LDK = 136, LDV = 72, LDP = 72;
  __shared__ __align__(16) unsigned short Ks[64*LDK];    // 17408 B
  __shared__ __align__(16) unsigned short Vt[128*LDV];   // 18432 B
  __shared__ __align__(16) unsigned short Pw[4][16*LDP]; //  9216 B
  const int i0 = blockIdx.x*64, jh = blockIdx.y, n = blockIdx.z;
  const int t = threadIdx.x, w = t>>6, lane = t&63, lr = lane&15, q4 = lane>>4;
  size_t base = (size_t)n*384*4096;
  const unsigned short* vtg = vtg_all + (size_t)n*128*4096;
  bfrag qf[4];   // Q row per (w,lr); serves as B[k=d][n=i]
  {
    const unsigned short* qrow = qkv + base + (size_t)(i0 + w*16 + lr)*384;
    #pragma unroll
    for (int kk=0;kk<4;++kk) qf[kk] = *(const bfrag*)(qrow + kk*32 + q4*8);
  }
  ffrag acc[8] = {};
  const float inv64 = 0.015625f;
  for (int j0 = jh*2048; j0 < jh*2048+2048; j0 += 64){
    __syncthreads();
    #pragma unroll
    for (int r=0;r<4;++r){                    // K rows j0..j0+63
      int pi = t + 256*r; int jl = pi>>4, seg = pi&15;
      *(uint4*)&Ks[jl*LDK + seg*8] = *(const uint4*)(qkv + base + (size_t)(j0+jl)*384 + 128 + seg*8);
    }
    #pragma unroll
    for (int r=0;r<4;++r){                    // Vt[128 d][64 j]
      int pi = t + 256*r; int d = pi>>3, c = pi&7;
      *(uint4*)&Vt[d*LDV + c*8] = *(const uint4*)(vtg + (size_t)d*4096 + j0 + c*8);
    }
    __syncthreads();
    #pragma unroll
    for (int jt=0;jt<4;++jt){
      ffrag s = {};
      #pragma unroll
      for (int kk=0;kk<4;++kk){
        bfrag kf = *(const bfrag*)&Ks[(jt*16+lr)*LDK + kk*32 + q4*8];  // A[m=j][k=d]
        s = MFMA(kf, qf[kk], s);               // D[m=j][n=i] = S^T tile
      }
      float p0 = __expf(s[0]*inv64);
      float p1 = __expf(s[1]*inv64);
      float p2 = __expf(s[2]*inv64);
      float p3 = __expf(s[3]*inv64);
      uint2 pk; pk.x = bfpack(p0,p1); pk.y = bfpack(p2,p3);
      *(uint2*)&Pw[w][lr*LDP + jt*16 + q4*4] = pk;   // P[i=lr][j] row, wave-private
    }
    asm volatile("" ::: "memory");             // no compiler reorder of Pw read above writes
    #pragma unroll
    for (int jk=0;jk<2;++jk){
      bfrag pf = *(const bfrag*)&Pw[w][lr*LDP + jk*32 + q4*8];         // B[k=j][n=i]
      #pragma unroll
      for (int dt=0;dt<8;++dt){
        bfrag af = *(const bfrag*)&Vt[(dt*16+lr)*LDV + jk*32 + q4*8];  // A[m=d][k=j]
        acc[dt] = MFMA(af, pf, acc[dt]);       // D[m=d][n=i]
      }
    }
  }
  unsigned short* po = part + (size_t)(jh*4+n)*524288;
  const int i = i0 + w*16 + lr;
  #pragma unroll
  for (int dt=0;dt<8;++dt){
    us4 pk;
    pk.x = f2bf(acc[dt][0]); pk.y = f2bf(acc[dt][1]);
    pk.z = f2bf(acc[dt][2]); pk.w = f2bf(acc[dt][3]);
    *(us4*)(po + (size_t)i*128 + dt*16 + q4*4) = pk;
  }
}

// ---------------- K6: output projection, sums 2 bf16 partial slices, c-tile 128 ----------------
__global__ __launch_bounds__(256) void k_oproj(const unsigned short* __restrict__ part,
                                               const unsigned short* __restrict__ Wob,
                                               const float* __restrict__ bo, float* __restrict__ y){
  constexpr int LD = 136;
  __shared__ __align__(16) unsigned short As[128*LD];  // Wo tile [c][e]
  __shared__ __align__(16) unsigned short Rt[64*LD];   // attn^T [hw][e]
  const int c0 = blockIdx.x*128, h0 = blockIdx.y*64, n = blockIdx.z;
  const int t = threadIdx.x, w = t>>6, lane = t&63, lr = lane&15, q4 = lane>>4;
  #pragma unroll
  for (int r=0;r<8;++r){
    int pi = t + 256*r; int cl = pi>>4, seg = pi&15;
    *(uint4*)&As[cl*LD + seg*8] = *(const uint4*)(Wob + (c0+cl)*128 + seg*8);
  }
  #pragma unroll
  for (int r=0;r<8;++r){                     // 2048 = 128 e x 16 h-quads
    int pi = t + 256*r; int e = pi>>4, h4 = pi&15;
    size_t f = (size_t)e*4096 + h0 + h4*4;
    float a0=0.f,a1=0.f,a2=0.f,a3=0.f;
    #pragma unroll
    for (int s=0;s<2;++s){
      uint2 u = *(const uint2*)(part + (size_t)(s*4+n)*524288 + f);
      a0 += bf2f((unsigned short)(u.x & 0xffffu));
      a1 += bf2f((unsigned short)(u.x >> 16));
      a2 += bf2f((unsigned short)(u.y & 0xffffu));
      a3 += bf2f((unsigned short)(u.y >> 16));
    }
    Rt[(h4*4+0)*LD + e] = f2bf(a0);
    Rt[(h4*4+1)*LD + e] = f2bf(a1);
    Rt[(h4*4+2)*LD + e] = f2bf(a2);
    Rt[(h4*4+3)*LD + e] = f2bf(a3);
  }
  __syncthreads();
  ffrag acc[8] = {};
  #pragma unroll
  for (int kk=0;kk<4;++kk){
    bfrag a = *(const bfrag*)&Rt[(w*16+lr)*LD + kk*32 + q4*8];   // A = attn^T rows (hw)
    #pragma unroll
    for (int cs=0;cs<8;++cs){
      bfrag b = *(const bfrag*)&As[(cs*16+lr)*LD + kk*32 + q4*8]; // B = Wo rows (c)
      acc[cs] = MFMA(a,b,acc[cs]);                                // D[m=hw][n=c]
    }
  }
  #pragma unroll
  for (int cs=0;cs<8;++cs){
    int c = c0 + cs*16 + lr;
    float bias = bo[c];
    float4 v4 = { acc[cs][0]+bias, acc[cs][1]+bias, acc[cs][2]+bias, acc[cs][3]+bias };
    *(float4*)(y + ((size_t)n*256 + c)*4096 + h0 + w*16 + q4*4) = v4;
  }
}

extern "C" void kernel_launch(void* const* d_in, const int* in_sizes, int n_in,
                              void* d_out, int out_size, void* d_ws, size_t ws_size,
                              hipStream_t stream){
  const float* x  = (const float*)d_in[0];
  const float* Wq = (const float*)d_in[1];
  const float* bq = (const float*)d_in[2];
  const float* Wo = (const float*)d_in[3];
  const float* bo = (const float*)d_in[4];
  float* y = (float*)d_out;
  char* ws = (char*)d_ws;
  unsigned short* qkv  = (unsigned short*)(ws + 0);          // 12,582,912
  unsigned short* vtg  = (unsigned short*)(ws + 12582912);   //  4,194,304
  unsigned short* Wqb  = (unsigned short*)(ws + 16777216);   //    196,608
  unsigned short* Wob  = (unsigned short*)(ws + 16973824);   //     65,536
  float* zp   = (float*)(ws + 17039360);                     //    524,288 (4n x 8ic x 4096)
  float* lse  = (float*)(ws + 17563648);                     //     65,536
  unsigned short* part = (unsigned short*)(ws + 17629184);   //  8,388,608 (2 bf16 slices) end ~26MB

  k_wcast <<<dim3(384),     256, 0, stream>>>(Wq, Wo, Wqb, Wob);
  k_qkv   <<<dim3(6,64,4),  256, 0, stream>>>(x, Wqb, bq, qkv);
  k_stats <<<dim3(32,8,4),  256, 0, stream>>>(qkv, zp);
  k_merge <<<dim3(64),      256, 0, stream>>>(zp, lse);
  k_vtrans<<<dim3(64,4),    256, 0, stream>>>(qkv, lse, vtg);
  k_attn  <<<dim3(64,2,4),  256, 0, stream>>>(qkv, vtg, part);
  k_oproj <<<dim3(2,64,4),  256, 0, stream>>>(part, Wob, bo, y);
}

// Round 6
// 209.014 us; speedup vs baseline: 1.5156x; 1.3853x over previous
//
#include <hip/hip_runtime.h>
#include <hip/hip_bf16.h>

// N=4, C=256, H=W=64 -> HW=4096, E=128, 3E=384.
// qkv flat [n][o][hw] IS [n][p][384]: q=p*384+0..127, k=+128, v=+256.
// attn flat [n][i*128+d] reinterpreted as [n][e][hw] by k_oproj (raw reshape).
// Column softmax (over i): scores s=q.k/64, |s|<~1.2 -> direct sum-exp (no max), lse=log(Z).

typedef short bfrag __attribute__((ext_vector_type(8)));   // 8 bf16 (4 VGPRs)
typedef float ffrag __attribute__((ext_vector_type(4)));   // 4 fp32 acc
typedef unsigned short us4 __attribute__((ext_vector_type(4)));
#define MFMA(a,b,c) __builtin_amdgcn_mfma_f32_16x16x32_bf16((a),(b),(c),0,0,0)

__device__ __forceinline__ unsigned short f2bf(float f){
  union { float f; unsigned u; } v; v.f = f;
  unsigned r = v.u + 0x7fffu + ((v.u >> 16) & 1u);   // RNE
  return (unsigned short)(r >> 16);
}
__device__ __forceinline__ float bf2f(unsigned short h){
  union { unsigned u; float f; } v; v.u = ((unsigned)h) << 16; return v.f;
}
__device__ __forceinline__ unsigned bfpack(float a, float b){
  return (unsigned)f2bf(a) | ((unsigned)f2bf(b) << 16);
}

// ---------------- K0: cast weights to bf16 ----------------
__global__ __launch_bounds__(256) void k_wcast(const float* __restrict__ Wq, const float* __restrict__ Wo,
                                               unsigned short* __restrict__ Wqb, unsigned short* __restrict__ Wob){
  int i = blockIdx.x*256 + threadIdx.x;
  if (i < 384*256) Wqb[i] = f2bf(Wq[i]);
  if (i < 256*128) Wob[i] = f2bf(Wo[i]);
}

// ---------------- K1: QKV projection (D[m=hw][n=o] -> ushort4 stores; float4 x staging) ----------------
__global__ __launch_bounds__(256) void k_qkv(const float* __restrict__ x, const unsigned short* __restrict__ Wqb,
                                             const float* __restrict__ bq, unsigned short* __restrict__ qkv){
  constexpr int LD = 136;
  __shared__ __align__(16) unsigned short As[64*LD];   // W tile [o][c-half]
  __shared__ __align__(16) unsigned short Bs[64*LD];   // X^T tile [hw][c-half]
  const int o0 = blockIdx.x*64, h0 = blockIdx.y*64, n = blockIdx.z;
  const int t = threadIdx.x, w = t>>6, lane = t&63, lr = lane&15, q4 = lane>>4;
  ffrag acc[4] = {};
  for (int kh = 0; kh < 2; ++kh) {
    __syncthreads();
    #pragma unroll
    for (int r=0;r<4;++r){
      int pi = t + 256*r; int o = pi>>4, seg = pi&15;
      *(uint4*)&As[o*LD + seg*8] = *(const uint4*)(Wqb + (o0+o)*256 + kh*128 + seg*8);
    }
    #pragma unroll
    for (int r=0;r<8;++r){                       // 2048 = 128 c x 16 h-quads, float4 loads
      int idx = t + 256*r; int cl = idx>>4, h4 = idx&15;
      float4 v = *(const float4*)(x + (size_t)(n*256 + kh*128 + cl)*4096 + h0 + h4*4);
      Bs[(h4*4+0)*LD + cl] = f2bf(v.x);
      Bs[(h4*4+1)*LD + cl] = f2bf(v.y);
      Bs[(h4*4+2)*LD + cl] = f2bf(v.z);
      Bs[(h4*4+3)*LD + cl] = f2bf(v.w);
    }
    __syncthreads();
    #pragma unroll
    for (int kk=0;kk<4;++kk){
      bfrag a = *(const bfrag*)&Bs[(w*16+lr)*LD + kk*32 + q4*8];   // A = x^T rows (hw)
      #pragma unroll
      for (int ot=0;ot<4;++ot){
        bfrag b = *(const bfrag*)&As[(ot*16+lr)*LD + kk*32 + q4*8]; // B = W rows (o)
        acc[ot] = MFMA(a,b,acc[ot]);                                // D[m=hw][n=o]
      }
    }
  }
  size_t base = (size_t)n*384*4096;
  #pragma unroll
  for (int ot=0;ot<4;++ot){
    int o  = o0 + ot*16 + lr;
    float bias = bq[o];
    int hw = h0 + w*16 + q4*4;
    us4 pk;
    pk.x = f2bf(acc[ot][0] + bias); pk.y = f2bf(acc[ot][1] + bias);
    pk.z = f2bf(acc[ot][2] + bias); pk.w = f2bf(acc[ot][3] + bias);
    *(us4*)(qkv + base + (size_t)o*4096 + hw) = pk;
  }
}

// ---------------- K2: global V transpose: vt[n][d][p] = v[n][p][d] ----------------
__global__ __launch_bounds__(256) void k_vtrans(const unsigned short* __restrict__ qkv, unsigned short* __restrict__ vt){
  constexpr int LD = 136;
  __shared__ __align__(16) unsigned short T[64*LD];
  const int p0 = blockIdx.x*64, n = blockIdx.y;
  const int t = threadIdx.x;
  size_t base = (size_t)n*384*4096;
  #pragma unroll
  for (int r=0;r<4;++r){
    int pi = t + 256*r; int pl = pi>>4, seg = pi&15;
    *(uint4*)&T[pl*LD + seg*8] = *(const uint4*)(qkv + base + (size_t)(p0+pl)*384 + 256 + seg*8);
  }
  __syncthreads();
  unsigned* vt32 = (unsigned*)(vt + (size_t)n*128*4096);
  #pragma unroll
  for (int r=0;r<16;++r){
    int pi = t + 256*r;            // 4096 = 128 d x 32 p-pairs
    int d = pi>>5, k = pi&31;
    unsigned lo = T[(2*k)*LD + d];
    unsigned hi = T[(2*k+1)*LD + d];
    vt32[(size_t)d*2048 + (p0>>1) + k] = lo | (hi<<16);
  }
}

// ---------------- K3: column Z partials: Z_j = sum_i exp(q_i.k_j/64) (no max; bounded scores) ----------------
__global__ __launch_bounds__(256) void k_stats(const unsigned short* __restrict__ qkv,
                                               float* __restrict__ zp){
  constexpr int LD = 136;
  __shared__ __align__(16) unsigned short Qs[64*LD];   // 17408 B
  const int j0 = blockIdx.x*128, ic = blockIdx.y, n = blockIdx.z;
  const int t = threadIdx.x, w = t>>6, lane = t&63, lr = lane&15, q4 = lane>>4;
  size_t base = (size_t)n*384*4096;
  bfrag kf[2][4];
  #pragma unroll
  for (int js=0; js<2; ++js){
    const unsigned short* krow = qkv + base + (size_t)(j0 + w*32 + js*16 + lr)*384 + 128;
    #pragma unroll
    for (int kk=0;kk<4;++kk) kf[js][kk] = *(const bfrag*)(krow + kk*32 + q4*8);
  }
  float Zc[8] = {};                       // [js*4 + r]
  const float inv64 = 0.015625f;
  for (int rnd=0; rnd<8; ++rnd){          // 8 x 64-i stage rounds (ic chunk = 512 i)
    int i0 = (ic<<9) + rnd*64;
    __syncthreads();
    #pragma unroll
    for (int r=0;r<4;++r){
      int pi = t + 256*r; int il = pi>>4, seg = pi&15;
      *(uint4*)&Qs[il*LD + seg*8] = *(const uint4*)(qkv + base + (size_t)(i0+il)*384 + seg*8);
    }
    __syncthreads();
    #pragma unroll
    for (int it=0; it<4; ++it){
      bfrag qb[4];
      #pragma unroll
      for (int kk=0;kk<4;++kk) qb[kk] = *(const bfrag*)&Qs[(it*16+lr)*LD + kk*32 + q4*8];
      #pragma unroll
      for (int js=0; js<2; ++js){
        ffrag s = {};
        #pragma unroll
        for (int kk=0;kk<4;++kk) s = MFMA(kf[js][kk], qb[kk], s);   // D[m=j][n=i]
        #pragma unroll
        for (int r=0;r<4;++r) Zc[js*4+r] += __expf(s[r]*inv64);
      }
    }
  }
  #pragma unroll
  for (int v=0; v<8; ++v){
    float z = Zc[v];
    z += __shfl_xor(z, 1); z += __shfl_xor(z, 2);
    z += __shfl_xor(z, 4); z += __shfl_xor(z, 8);
    Zc[v] = z;
  }
  if (lr == 0){
    int jb = j0 + w*32;
    float* zrow = zp + (size_t)((n<<3)+ic)*4096;
    #pragma unroll
    for (int js=0; js<2; ++js)
      #pragma unroll
      for (int r=0;r<4;++r)
        zrow[jb + js*16 + q4*4 + r] = Zc[js*4+r];
  }
}

// ---------------- K4: merge partial Z -> lse[n][j] = log(sum Z) ----------------
__global__ __launch_bounds__(256) void k_merge(const float* __restrict__ zp, float* __restrict__ lse){
  int idx = blockIdx.x*256 + threadIdx.x;   // n*4096 + j
  int n = idx>>12, j = idx&4095;
  float Z = 0.f;
  #pragma unroll
  for (int c=0;c<8;++c) Z += zp[(size_t)((n<<3)+c)*4096 + j];
  lse[idx] = __logf(Z);
}

// ---------------- K5: PV pass — exact round-3 structure (measured 78.6 us) ----------------
// QK: D[m=j][n=i] = MFMA(K,Q); P = exp(s/64 - lse_j); PV: D[m=d][n=i] = MFMA(Vt,P); fp32 partials.
__global__ __launch_bounds__(256) void k_attn(const unsigned short* __restrict__ qkv,
                                              const unsigned short* __restrict__ vtg_all,
                                              const float* __restrict__ lse,
                                              float* __restrict__ part){
  constexpr int LDK = 136, LDV = 72, LDP = 72;
  __shared__ __align__(16) unsigned short Ks[64*LDK];    // 17408 B
  __shared__ __align__(16) unsigned short Vt[128*LDV];   // 18432 B
  __shared__ __align__(16) unsigned short Pw[4][16*LDP]; //  9216 B
  __shared__ float Ls[64];
  const int i0 = blockIdx.x*64, jh = blockIdx.y, n = blockIdx.z;
  const int t = threadIdx.x, w = t>>6, lane = t&63, lr = lane&15, q4 = lane>>4;
  size_t base = (size_t)n*384*4096;
  const unsigned short* vtg = vtg_all + (size_t)n*128*4096;
  const float* lsen = lse + (n<<12);
  bfrag qf[4];   // Q row per (w,lr); serves as B[k=d][n=i]
  {
    const unsigned short* qrow = qkv + base + (size_t)(i0 + w*16 + lr)*384;
    #pragma unroll
    for (int kk=0;kk<4;++kk) qf[kk] = *(const bfrag*)(qrow + kk*32 + q4*8);
  }
  ffrag acc[8] = {};
  const float inv64 = 0.015625f;
  for (int j0 = jh*2048; j0 < jh*2048+2048; j0 += 64){
    __syncthreads();
    #pragma unroll
    for (int r=0;r<4;++r){                    // K rows j0..j0+63
      int pi = t + 256*r; int jl = pi>>4, seg = pi&15;
      *(uint4*)&Ks[jl*LDK + seg*8] = *(const uint4*)(qkv + base + (size_t)(j0+jl)*384 + 128 + seg*8);
    }
    #pragma unroll
    for (int r=0;r<4;++r){                    // Vt[128 d][64 j]
      int pi = t + 256*r; int d = pi>>3, c = pi&7;
      *(uint4*)&Vt[d*LDV + c*8] = *(const uint4*)(vtg + (size_t)d*4096 + j0 + c*8);
    }
    if (t < 64) Ls[t] = lsen[j0 + t];
    __syncthreads();
    #pragma unroll
    for (int jt=0;jt<4;++jt){
      ffrag s = {};
      #pragma unroll
      for (int kk=0;kk<4;++kk){
        bfrag kf = *(const bfrag*)&Ks[(jt*16+lr)*LDK + kk*32 + q4*8];  // A[m=j][k=d]
        s = MFMA(kf, qf[kk], s);               // D[m=j][n=i] = S^T tile
      }
      float4 l4 = *(const float4*)&Ls[jt*16 + q4*4];
      float p0 = __expf(s[0]*inv64 - l4.x);
      float p1 = __expf(s[1]*inv64 - l4.y);
      float p2 = __expf(s[2]*inv64 - l4.z);
      float p3 = __expf(s[3]*inv64 - l4.w);
      uint2 pk; pk.x = bfpack(p0,p1); pk.y = bfpack(p2,p3);
      *(uint2*)&Pw[w][lr*LDP + jt*16 + q4*4] = pk;   // P[i=lr][j] row, wave-private
    }
    asm volatile("" ::: "memory");             // no compiler reorder of Pw read above writes
    #pragma unroll
    for (int jk=0;jk<2;++jk){
      bfrag pf = *(const bfrag*)&Pw[w][lr*LDP + jk*32 + q4*8];         // B[k=j][n=i]
      #pragma unroll
      for (int dt=0;dt<8;++dt){
        bfrag af = *(const bfrag*)&Vt[(dt*16+lr)*LDV + jk*32 + q4*8];  // A[m=d][k=j]
        acc[dt] = MFMA(af, pf, acc[dt]);       // D[m=d][n=i]
      }
    }
  }
  float* po = part + (size_t)(jh*4+n)*524288;
  const int i = i0 + w*16 + lr;
  #pragma unroll
  for (int dt=0;dt<8;++dt){
    float4 v4 = { acc[dt][0], acc[dt][1], acc[dt][2], acc[dt][3] };
    *(float4*)(po + (size_t)i*128 + dt*16 + q4*4) = v4;
  }
}

// ---------------- K6: output projection, fuses 2 fp32 partial slices, c-tile 128 ----------------
__global__ __launch_bounds__(256) void k_oproj(const float* __restrict__ part,
                                               const unsigned short* __restrict__ Wob,
                                               const float* __restrict__ bo, float* __restrict__ y){
  constexpr int LD = 136;
  __shared__ __align__(16) unsigned short As[128*LD];  // Wo tile [c][e]
  __shared__ __align__(16) unsigned short Rt[64*LD];   // attn^T [hw][e]
  const int c0 = blockIdx.x*128, h0 = blockIdx.y*64, n = blockIdx.z;
  const int t = threadIdx.x, w = t>>6, lane = t&63, lr = lane&15, q4 = lane>>4;
  const float* p0 = part + (size_t)n*524288;
  const float* p1 = part + (size_t)(4+n)*524288;
  #pragma unroll
  for (int r=0;r<8;++r){
    int pi = t + 256*r; int cl = pi>>4, seg = pi&15;
    *(uint4*)&As[cl*LD + seg*8] = *(const uint4*)(Wob + (c0+cl)*128 + seg*8);
  }
  #pragma unroll
  for (int r=0;r<16;++r){                    // read [e][hw] view of part, sum halves, transpose
    int pi = t + 256*r; int e = pi>>5, h2 = pi&31;
    size_t f = (size_t)e*4096 + h0 + h2*2;
    float a0 = p0[f]   + p1[f];
    float a1 = p0[f+1] + p1[f+1];
    Rt[(h2*2)*LD + e]   = f2bf(a0);
    Rt[(h2*2+1)*LD + e] = f2bf(a1);
  }
  __syncthreads();
  ffrag acc[8] = {};
  #pragma unroll
  for (int kk=0;kk<4;++kk){
    bfrag a = *(const bfrag*)&Rt[(w*16+lr)*LD + kk*32 + q4*8];   // A = attn^T rows (hw)
    #pragma unroll
    for (int cs=0;cs<8;++cs){
      bfrag b = *(const bfrag*)&As[(cs*16+lr)*LD + kk*32 + q4*8]; // B = Wo rows (c)
      acc[cs] = MFMA(a,b,acc[cs]);                                // D[m=hw][n=c]
    }
  }
  #pragma unroll
  for (int cs=0;cs<8;++cs){
    int c = c0 + cs*16 + lr;
    float bias = bo[c];
    float4 v4 = { acc[cs][0]+bias, acc[cs][1]+bias, acc[cs][2]+bias, acc[cs][3]+bias };
    *(float4*)(y + ((size_t)n*256 + c)*4096 + h0 + w*16 + q4*4) = v4;
  }
}

extern "C" void kernel_launch(void* const* d_in, const int* in_sizes, int n_in,
                              void* d_out, int out_size, void* d_ws, size_t ws_size,
                              hipStream_t stream){
  const float* x  = (const float*)d_in[0];
  const float* Wq = (const float*)d_in[1];
  const float* bq = (const float*)d_in[2];
  const float* Wo = (const float*)d_in[3];
  const float* bo = (const float*)d_in[4];
  float* y = (float*)d_out;
  char* ws = (char*)d_ws;
  unsigned short* qkv  = (unsigned short*)(ws + 0);          // 12,582,912
  unsigned short* vtg  = (unsigned short*)(ws + 12582912);   //  4,194,304
  unsigned short* Wqb  = (unsigned short*)(ws + 16777216);   //    196,608
  unsigned short* Wob  = (unsigned short*)(ws + 16973824);   //     65,536
  float* zp   = (float*)(ws + 17039360);                     //    524,288 (4n x 8ic x 4096)
  float* lse  = (float*)(ws + 17563648);                     //     65,536
  float* part = (float*)(ws + 17629184);                     // 16,777,216 (2 fp32 slices) end ~34.4MB

  k_wcast <<<dim3(384),     256, 0, stream>>>(Wq, Wo, Wqb, Wob);
  k_qkv   <<<dim3(6,64,4),  256, 0, stream>>>(x, Wqb, bq, qkv);
  k_vtrans<<<dim3(64,4),    256, 0, stream>>>(qkv, vtg);
  k_stats <<<dim3(32,8,4),  256, 0, stream>>>(qkv, zp);
  k_merge <<<dim3(64),      256, 0, stream>>>(zp, lse);
  k_attn  <<<dim3(64,2,4),  256, 0, stream>>>(qkv, vtg, lse, part);
  k_oproj <<<dim3(2,64,4),  256, 0, stream>>>(part, Wob, bo, y);
}